// Round 2
// baseline (257.270 us; speedup 1.0000x reference)
//
#include <hip/hip_runtime.h>

#define Bb 16
#define Tt 12
#define Nn 1024
#define FIN 32
#define FOUT 64
#define KC 3
#define KJ (KC * Nn)     // 3072 — GEMM K dimension (k,j)
#define NO (Tt * FOUT)   // 768  — GEMM N dimension (t,o)

#define BM 128
#define BN 128
#define BK 64
#define NKT (KJ / BK)    // 48 K-tiles

typedef __attribute__((ext_vector_type(8))) short short8;
typedef __attribute__((ext_vector_type(4))) float f32x4;

__device__ __forceinline__ unsigned short f2bf(float f) {
  union { float f; unsigned u; } v; v.f = f;
  unsigned r = v.u + 0x7FFFu + ((v.u >> 16) & 1u);  // RNE
  return (unsigned short)(r >> 16);
}

// ---------------------------------------------------------------------------
// k1: A[b][i][k*N+j] = bf16(cheb[k,i,j] * att[b,i,j])
// ---------------------------------------------------------------------------
__global__ __launch_bounds__(256) void k1_build_A(
    const float* __restrict__ att, const float* __restrict__ cheb,
    unsigned short* __restrict__ Acat) {
  unsigned idx = blockIdx.x * 256u + threadIdx.x;  // (b, i, j/4)
  const int j = (idx & 255u) << 2;
  const int i = (idx >> 8) & 1023u;
  const int b = idx >> 18;
  const float4 av = *(const float4*)(att + ((size_t)b * Nn + i) * Nn + j);
  const size_t obase = ((size_t)b * Nn + i) * KJ + j;
#pragma unroll
  for (int k = 0; k < KC; ++k) {
    const float4 cv = *(const float4*)(cheb + ((size_t)k * Nn + i) * Nn + j);
    ushort4 o;
    o.x = f2bf(av.x * cv.x); o.y = f2bf(av.y * cv.y);
    o.z = f2bf(av.z * cv.z); o.w = f2bf(av.w * cv.w);
    *(ushort4*)(Acat + obase + (size_t)k * Nn) = o;
  }
}

// ---------------------------------------------------------------------------
// k2: Y[b][t*64+o][k*N+j] = bf16( sum_f x[b,t,j,f] * Theta[k,f,o] )
// ---------------------------------------------------------------------------
__global__ __launch_bounds__(256) void k2_build_Y(
    const float* __restrict__ x, const float* __restrict__ theta,
    unsigned short* __restrict__ Yw) {
  __shared__ float th[KC * FOUT * FIN];  // [k][o][f]
  const int tid = threadIdx.x;
  for (int s = tid; s < KC * FOUT * FIN; s += 256) {
    const int k = s >> 11, rem = s & 2047, o = rem >> 5, f = rem & 31;
    th[s] = theta[(k * FIN + f) * FOUT + o];
  }
  __syncthreads();
  const int blk = blockIdx.x;
  const int half = blk & 1, bt = blk >> 1;
  const int t = bt % Tt, b = bt / Tt;
  const int j0 = half * 512 + tid * 2;
  const float* xp = x + ((size_t)(b * Tt + t) * Nn + j0) * FIN;
  float x0[FIN], x1[FIN];
#pragma unroll
  for (int q = 0; q < FIN / 4; ++q) {
    float4 v = *(const float4*)(xp + 4 * q);
    x0[4 * q] = v.x; x0[4 * q + 1] = v.y; x0[4 * q + 2] = v.z; x0[4 * q + 3] = v.w;
    float4 u = *(const float4*)(xp + FIN + 4 * q);
    x1[4 * q] = u.x; x1[4 * q + 1] = u.y; x1[4 * q + 2] = u.z; x1[4 * q + 3] = u.w;
  }
  const size_t ybase = (size_t)(b * NO + t * FOUT) * KJ;
  for (int k = 0; k < KC; ++k) {
    for (int o = 0; o < FOUT; ++o) {
      const float* tp = &th[(k * FOUT + o) * FIN];
      float a0 = 0.f, a1 = 0.f;
#pragma unroll
      for (int q = 0; q < FIN / 4; ++q) {
        float4 tv = *(const float4*)(tp + 4 * q);
        a0 = fmaf(x0[4 * q + 0], tv.x, a0); a1 = fmaf(x1[4 * q + 0], tv.x, a1);
        a0 = fmaf(x0[4 * q + 1], tv.y, a0); a1 = fmaf(x1[4 * q + 1], tv.y, a1);
        a0 = fmaf(x0[4 * q + 2], tv.z, a0); a1 = fmaf(x1[4 * q + 2], tv.z, a1);
        a0 = fmaf(x0[4 * q + 3], tv.w, a0); a1 = fmaf(x1[4 * q + 3], tv.w, a1);
      }
      const unsigned pack = (unsigned)f2bf(a0) | ((unsigned)f2bf(a1) << 16);
      *(unsigned*)(Yw + ybase + (size_t)o * KJ + k * Nn + j0) = pack;
    }
  }
}

// ---------------------------------------------------------------------------
// k3: per b: C[i, n] = sum_kj A[i,kj] * Y[n,kj], ReLU, scatter to out[b,t,i,o]
// 2-phase double-buffered pipeline (T3-minimum recipe): STAGE(t+1) issued
// before ds_read/MFMA of t; single vmcnt(0)+barrier per iter.
// ---------------------------------------------------------------------------
__global__ __launch_bounds__(256) void k3_gemm(
    const unsigned short* __restrict__ A, const unsigned short* __restrict__ Yw,
    float* __restrict__ out) {
  __shared__ unsigned short As[2][BM * BK];
  __shared__ unsigned short Bs[2][BN * BK];
  const int bid = blockIdx.x;
  const int swz = (bid & 7) * 96 + (bid >> 3);  // 768 blocks, bijective XCD chunking
  const int b = swz / 48;
  const int r = swz % 48;
  const int it = r / 6;
  const int nt = r % 6;
  const unsigned short* Ap = A + ((size_t)b * Nn + it * BM) * KJ;
  const unsigned short* Bp = Yw + ((size_t)b * NO + nt * BN) * KJ;
  const int tid = threadIdx.x;
  const int w = tid >> 6, l = tid & 63;
  const int wr = w >> 1, wc = w & 1;
  const int srow = l >> 3;      // row within 8-row staging group
  const int schunk = l & 7;     // 16B chunk within 128B row
  const int lrow = l & 15;
  const int lk0 = (l >> 4) * 8;

  f32x4 acc[4][4];
#pragma unroll
  for (int mi = 0; mi < 4; ++mi)
#pragma unroll
    for (int ni = 0; ni < 4; ++ni)
      acc[mi][ni] = (f32x4){0.f, 0.f, 0.f, 0.f};

  // ---- staging macro-ish lambda: stage K-tile kt into buffer bufi ----
  auto STAGE = [&](int bufi, int kt) {
    const int kofs = kt * BK;
#pragma unroll
    for (int g = 0; g < 4; ++g) {
      const int row = w * 32 + g * 8 + srow;
      __builtin_amdgcn_global_load_lds(
          (const __attribute__((address_space(1))) void*)(Ap + (size_t)row * KJ + kofs + schunk * 8),
          (__attribute__((address_space(3))) void*)(&As[bufi][(w * 32 + g * 8) * BK]),
          16, 0, 0);
    }
#pragma unroll
    for (int g = 0; g < 4; ++g) {
      const int row = w * 32 + g * 8 + srow;
      __builtin_amdgcn_global_load_lds(
          (const __attribute__((address_space(1))) void*)(Bp + (size_t)row * KJ + kofs + schunk * 8),
          (__attribute__((address_space(3))) void*)(&Bs[bufi][(w * 32 + g * 8) * BK]),
          16, 0, 0);
    }
  };

  auto COMPUTE = [&](int bufi) {
#pragma unroll
    for (int ks = 0; ks < 2; ++ks) {
      short8 af[4], bfr[4];
      const int lk = lk0 + ks * 32;
#pragma unroll
      for (int mi = 0; mi < 4; ++mi)
        af[mi] = *(const short8*)&As[bufi][(wr * 64 + mi * 16 + lrow) * BK + lk];
#pragma unroll
      for (int ni = 0; ni < 4; ++ni)
        bfr[ni] = *(const short8*)&Bs[bufi][(wc * 64 + ni * 16 + lrow) * BK + lk];
#pragma unroll
      for (int mi = 0; mi < 4; ++mi)
#pragma unroll
        for (int ni = 0; ni < 4; ++ni)
          acc[mi][ni] = __builtin_amdgcn_mfma_f32_16x16x32_bf16(af[mi], bfr[ni], acc[mi][ni], 0, 0, 0);
    }
  };

  // prologue
  STAGE(0, 0);
  asm volatile("s_waitcnt vmcnt(0)");
  __syncthreads();

  int cur = 0;
  for (int kt = 0; kt < NKT - 1; ++kt) {
    STAGE(cur ^ 1, kt + 1);   // prefetch next tile — flies under this tile's compute
    COMPUTE(cur);             // compiler inserts lgkmcnt before MFMA deps
    asm volatile("s_waitcnt vmcnt(0)");
    __syncthreads();
    cur ^= 1;
  }
  COMPUTE(cur);               // epilogue tile, no prefetch

  const int rbase = it * BM + wr * 64;
  const int cbase = nt * BN + wc * 64;
#pragma unroll
  for (int mi = 0; mi < 4; ++mi) {
#pragma unroll
    for (int ni = 0; ni < 4; ++ni) {
      const int col = cbase + ni * 16 + lrow;   // n = t*64 + o
      const int t = col >> 6, o = col & 63;
      const int row0 = rbase + mi * 16 + ((l >> 4) << 2);
      float* op = out + ((size_t)(b * Tt + t) * Nn + row0) * FOUT + o;
      f32x4 v = acc[mi][ni];
#pragma unroll
      for (int q = 0; q < 4; ++q)
        op[(size_t)q * FOUT] = fmaxf(v[q], 0.f);
    }
  }
}

// ---------------------------------------------------------------------------
// fallback (ws too small): slow but correct, pure f32
// ---------------------------------------------------------------------------
__global__ __launch_bounds__(128) void k_fallback(
    const float* __restrict__ x, const float* __restrict__ att,
    const float* __restrict__ cheb, const float* __restrict__ theta,
    float* __restrict__ out) {
  const int blk = blockIdx.x;  // (b, t, i)
  const int i = blk & 1023;
  const int bt = blk >> 10;
  const int t = bt % Tt, b = bt / Tt;
  __shared__ float rhs[KC * FIN];
  const int tid = threadIdx.x;
  if (tid < KC * FIN) {
    const int k = tid >> 5, f = tid & 31;
    const float* ar = att + ((size_t)b * Nn + i) * Nn;
    const float* cr = cheb + ((size_t)k * Nn + i) * Nn;
    const float* xr = x + ((size_t)(b * Tt + t) * Nn) * FIN + f;
    float s = 0.f;
    for (int j = 0; j < Nn; ++j) s = fmaf(ar[j] * cr[j], xr[(size_t)j * FIN], s);
    rhs[tid] = s;
  }
  __syncthreads();
  if (tid < FOUT) {
    float a = 0.f;
#pragma unroll
    for (int kf = 0; kf < KC * FIN; ++kf) a = fmaf(rhs[kf], theta[kf * FOUT + tid], a);
    out[((size_t)(b * Tt + t) * Nn + i) * FOUT + tid] = fmaxf(a, 0.f);
  }
}

extern "C" void kernel_launch(void* const* d_in, const int* in_sizes, int n_in,
                              void* d_out, int out_size, void* d_ws, size_t ws_size,
                              hipStream_t stream) {
  const float* x     = (const float*)d_in[0];
  const float* att   = (const float*)d_in[1];
  const float* cheb  = (const float*)d_in[2];
  const float* theta = (const float*)d_in[3];
  float* out = (float*)d_out;

  const size_t needA = (size_t)Bb * Nn * KJ * sizeof(unsigned short);  // 96 MB
  const size_t needY = (size_t)Bb * NO * KJ * sizeof(unsigned short);  // 72 MB
  if (ws_size >= needA + needY) {
    unsigned short* Acat = (unsigned short*)d_ws;
    unsigned short* Yw   = (unsigned short*)((char*)d_ws + needA);
    hipLaunchKernelGGL(k1_build_A, dim3(Bb * Nn * (Nn / 4) / 256), dim3(256), 0, stream,
                       att, cheb, Acat);
    hipLaunchKernelGGL(k2_build_Y, dim3(Bb * Tt * 2), dim3(256), 0, stream,
                       x, theta, Yw);
    hipLaunchKernelGGL(k3_gemm, dim3(Bb * (Nn / BM) * (NO / BN)), dim3(256), 0, stream,
                       Acat, Yw, out);
  } else {
    hipLaunchKernelGGL(k_fallback, dim3(Bb * Tt * Nn), dim3(128), 0, stream,
                       x, att, cheb, theta, out);
  }
}

// Round 3
// 185.228 us; speedup vs baseline: 1.3889x; 1.3889x over previous
//
#include <hip/hip_runtime.h>

#define Bb 16
#define Tt 12
#define Nn 1024
#define FIN 32
#define FOUT 64
#define KC 3
#define KJ (KC * Nn)     // 3072 — GEMM K dimension (k,j)
#define NO (Tt * FOUT)   // 768  — GEMM N dimension (t,o)

#define BM 256
#define BN 256
#define BK 64
#define NKT (KJ / BK)    // 48 K-tiles

typedef __attribute__((ext_vector_type(8))) short short8;
typedef __attribute__((ext_vector_type(4))) float f32x4;

__device__ __forceinline__ unsigned short f2bf(float f) {
  union { float f; unsigned u; } v; v.f = f;
  unsigned r = v.u + 0x7FFFu + ((v.u >> 16) & 1u);  // RNE
  return (unsigned short)(r >> 16);
}

__device__ __forceinline__ void BAR() {
  __builtin_amdgcn_sched_barrier(0);
  __builtin_amdgcn_s_barrier();
  __builtin_amdgcn_sched_barrier(0);
}

// ---------------------------------------------------------------------------
// k1: A[b][i][k*N+j] = bf16(cheb[k,i,j] * att[b,i,j])
// ---------------------------------------------------------------------------
__global__ __launch_bounds__(256) void k1_build_A(
    const float* __restrict__ att, const float* __restrict__ cheb,
    unsigned short* __restrict__ Acat) {
  unsigned idx = blockIdx.x * 256u + threadIdx.x;  // (b, i, j/4)
  const int j = (idx & 255u) << 2;
  const int i = (idx >> 8) & 1023u;
  const int b = idx >> 18;
  const float4 av = *(const float4*)(att + ((size_t)b * Nn + i) * Nn + j);
  const size_t obase = ((size_t)b * Nn + i) * KJ + j;
#pragma unroll
  for (int k = 0; k < KC; ++k) {
    const float4 cv = *(const float4*)(cheb + ((size_t)k * Nn + i) * Nn + j);
    ushort4 o;
    o.x = f2bf(av.x * cv.x); o.y = f2bf(av.y * cv.y);
    o.z = f2bf(av.z * cv.z); o.w = f2bf(av.w * cv.w);
    *(ushort4*)(Acat + obase + (size_t)k * Nn) = o;
  }
}

// ---------------------------------------------------------------------------
// k2: Y[b][t*64+o][k*N+j] = bf16( sum_f x[b,t,j,f] * Theta[k,f,o] )
// ---------------------------------------------------------------------------
__global__ __launch_bounds__(256) void k2_build_Y(
    const float* __restrict__ x, const float* __restrict__ theta,
    unsigned short* __restrict__ Yw) {
  __shared__ float th[KC * FOUT * FIN];  // [k][o][f]
  const int tid = threadIdx.x;
  for (int s = tid; s < KC * FOUT * FIN; s += 256) {
    const int k = s >> 11, rem = s & 2047, o = rem >> 5, f = rem & 31;
    th[s] = theta[(k * FIN + f) * FOUT + o];
  }
  __syncthreads();
  const int blk = blockIdx.x;
  const int half = blk & 1, bt = blk >> 1;
  const int t = bt % Tt, b = bt / Tt;
  const int j0 = half * 512 + tid * 2;
  const float* xp = x + ((size_t)(b * Tt + t) * Nn + j0) * FIN;
  float x0[FIN], x1[FIN];
#pragma unroll
  for (int q = 0; q < FIN / 4; ++q) {
    float4 v = *(const float4*)(xp + 4 * q);
    x0[4 * q] = v.x; x0[4 * q + 1] = v.y; x0[4 * q + 2] = v.z; x0[4 * q + 3] = v.w;
    float4 u = *(const float4*)(xp + FIN + 4 * q);
    x1[4 * q] = u.x; x1[4 * q + 1] = u.y; x1[4 * q + 2] = u.z; x1[4 * q + 3] = u.w;
  }
  const size_t ybase = (size_t)(b * NO + t * FOUT) * KJ;
  for (int k = 0; k < KC; ++k) {
    for (int o = 0; o < FOUT; ++o) {
      const float* tp = &th[(k * FOUT + o) * FIN];
      float a0 = 0.f, a1 = 0.f;
#pragma unroll
      for (int q = 0; q < FIN / 4; ++q) {
        float4 tv = *(const float4*)(tp + 4 * q);
        a0 = fmaf(x0[4 * q + 0], tv.x, a0); a1 = fmaf(x1[4 * q + 0], tv.x, a1);
        a0 = fmaf(x0[4 * q + 1], tv.y, a0); a1 = fmaf(x1[4 * q + 1], tv.y, a1);
        a0 = fmaf(x0[4 * q + 2], tv.z, a0); a1 = fmaf(x1[4 * q + 2], tv.z, a1);
        a0 = fmaf(x0[4 * q + 3], tv.w, a0); a1 = fmaf(x1[4 * q + 3], tv.w, a1);
      }
      const unsigned pack = (unsigned)f2bf(a0) | ((unsigned)f2bf(a1) << 16);
      *(unsigned*)(Yw + ybase + (size_t)o * KJ + k * Nn + j0) = pack;
    }
  }
}

// ---------------------------------------------------------------------------
// k3: per b: C[i,n] = sum_kj A[i,kj]·Y[n,kj], ReLU, scatter to out[b,t,i,o].
// 256² tile, 8 waves (2M×4N, per-wave 128×64), BK=64, 4 phases/K-tile,
// derived-waits pipeline: one vmcnt(6) per K-tile (3 half-tiles in flight,
// never drained to 0), T2 XOR-swizzle (pre-swizzled global source + swizzled
// ds_read), T5 setprio around MFMA clusters.
//
// Stage stream (steady state, offsets relative to tile τ's q0):
//   A1(τ) @ -4 (= q0 of τ-1) | B0(τ) @ -6 (q2 of τ-2) | A0(τ),B1(τ) @ -5 (q3 of τ-2)
// vmcnt(6) at q3 end ⇒ the 6 newest loads (q2's 2 + q3's 4) may fly;
// everything older (incl. next tile's A1) landed before the q0 barrier.
// ---------------------------------------------------------------------------
__global__ __launch_bounds__(512, 2) void k3_gemm(
    const unsigned short* __restrict__ A, const unsigned short* __restrict__ Yw,
    float* __restrict__ out) {
  __shared__ __align__(16) unsigned short lds[65536];  // 128 KiB: A 64K, B 64K
  const int bid = blockIdx.x;
  const int logical = (bid & 7) * 24 + (bid >> 3);     // 192 = 8×24, bijective XCD chunking
  const int b  = logical / 12;
  const int r  = logical % 12;
  const int it = r / 3;
  const int nt = r % 3;
  const unsigned short* Ap = A  + ((size_t)b * Nn + it * BM) * KJ;
  const unsigned short* Bp = Yw + ((size_t)b * NO + nt * BN) * KJ;
  const int tid = threadIdx.x;
  const int w = tid >> 6, l = tid & 63;
  const int wm = w >> 2, wn = w & 3;     // 2 M-warps × 4 N-warps
  const int lrow = l & 15;
  const int c0 = l >> 4;                 // k-chunk base 0..3
  const int sx = lrow & 7;               // swizzle key (row & 7)

  f32x4 acc[8][4];
#pragma unroll
  for (int mi = 0; mi < 8; ++mi)
#pragma unroll
    for (int ni = 0; ni < 4; ++ni)
      acc[mi][ni] = (f32x4){0.f, 0.f, 0.f, 0.f};

  // LDS layout (ushort units): A half-tile slot (d,h) at (d*2+h)*8192; B at +32768.
  // Half-tile = 128 rows × 64 cols bf16, linear [row][chunk] where the CONTENT
  // of chunk c is global chunk c ^ (row&7) (inverse-swizzled source, rule #21).
  auto STAGE = [&](const unsigned short* gp, int lbase, int kt, int rowbase) {
#pragma unroll
    for (int g = 0; g < 2; ++g) {
      const int flat = g * 512 + w * 64 + l;   // 0..1023 = row*8 + cdst
      const int row  = flat >> 3;
      const int csrc = (flat & 7) ^ (row & 7);
      __builtin_amdgcn_global_load_lds(
          (const __attribute__((address_space(1))) void*)(gp + (size_t)(rowbase + row) * KJ + kt * BK + csrc * 8),
          (__attribute__((address_space(3))) void*)(lds + lbase + (g * 512 + w * 64) * 8),
          16, 0, 0);
    }
  };

  auto LDA = [&](int d, int mi, int ks) -> short8 {
    const int rh = mi * 16 + lrow;                 // row within my A-half (wm)
    const int ch = (c0 | (ks << 2)) ^ sx;          // swizzled chunk
    return *(const short8*)&lds[(d * 2 + wm) * 8192 + rh * 64 + ch * 8];
  };
  auto LDB = [&](int d, int ni, int ks) -> short8 {
    const int rb = wn * 64 + ni * 16 + lrow;       // 0..255 B-row (= C col)
    const int ch = (c0 | (ks << 2)) ^ sx;
    return *(const short8*)&lds[32768 + (d * 2 + (rb >> 7)) * 8192 + (rb & 127) * 64 + ch * 8];
  };

  // ---- prologue: issue 7 half-tiles in stream order, wait to 6 outstanding ----
  STAGE(Bp, 32768 + 0 * 8192, 0, 0);    // B0(0)
  STAGE(Ap, 0 * 8192,         0, 0);    // A0(0)
  STAGE(Bp, 32768 + 1 * 8192, 0, 128);  // B1(0)
  STAGE(Ap, 1 * 8192,         0, 128);  // A1(0)
  STAGE(Bp, 32768 + 2 * 8192, 1, 0);    // B0(1)
  STAGE(Ap, 2 * 8192,         1, 0);    // A0(1)
  STAGE(Bp, 32768 + 3 * 8192, 1, 128);  // B1(1)
  asm volatile("s_waitcnt vmcnt(6)" ::: "memory");  // tile 0 fully resident
  BAR();

  auto TILE = [&](int d, int tau) {
    const int t1 = (tau + 1 < NKT) ? tau + 1 : NKT - 1;  // clamped tail re-loads are
    const int t2 = (tau + 2 < NKT) ? tau + 2 : NKT - 1;  // write-after-last-read safe
    short8 a0[4], b0[4], a1[4], b1[4], a2[8];
    // ---- q0: read A m0-3 ks0 + B ks0; stage A1(tau+1) -> dbuf d^1 ----
#pragma unroll
    for (int mi = 0; mi < 4; ++mi) a0[mi] = LDA(d, mi, 0);
#pragma unroll
    for (int ni = 0; ni < 4; ++ni) b0[ni] = LDB(d, ni, 0);
    __builtin_amdgcn_sched_barrier(0);
    STAGE(Ap, ((d ^ 1) * 2 + 1) * 8192, t1, 128);
    __builtin_amdgcn_sched_barrier(0);
    BAR();
    __builtin_amdgcn_s_setprio(1);
#pragma unroll
    for (int mi = 0; mi < 4; ++mi)
#pragma unroll
      for (int ni = 0; ni < 4; ++ni)
        acc[mi][ni] = __builtin_amdgcn_mfma_f32_16x16x32_bf16(a0[mi], b0[ni], acc[mi][ni], 0, 0, 0);
    __builtin_amdgcn_s_setprio(0);
    BAR();
    // ---- q1: read A m4-7 ks0 + B ks1; no stage ----
#pragma unroll
    for (int mi = 0; mi < 4; ++mi) a1[mi] = LDA(d, mi + 4, 0);
#pragma unroll
    for (int ni = 0; ni < 4; ++ni) b1[ni] = LDB(d, ni, 1);
    BAR();
    __builtin_amdgcn_s_setprio(1);
#pragma unroll
    for (int mi = 0; mi < 4; ++mi)
#pragma unroll
      for (int ni = 0; ni < 4; ++ni)
        acc[mi + 4][ni] = __builtin_amdgcn_mfma_f32_16x16x32_bf16(a1[mi], b0[ni], acc[mi + 4][ni], 0, 0, 0);
    __builtin_amdgcn_s_setprio(0);
    BAR();
    // ---- q2: read A m0-7 ks1; stage B0(tau+2) -> dbuf d ----
#pragma unroll
    for (int mi = 0; mi < 8; ++mi) a2[mi] = LDA(d, mi, 1);
    __builtin_amdgcn_sched_barrier(0);
    STAGE(Bp, 32768 + (d * 2 + 0) * 8192, t2, 0);
    __builtin_amdgcn_sched_barrier(0);
    BAR();
    __builtin_amdgcn_s_setprio(1);
#pragma unroll
    for (int mi = 0; mi < 4; ++mi)
#pragma unroll
      for (int ni = 0; ni < 4; ++ni)
        acc[mi + 4][ni] = __builtin_amdgcn_mfma_f32_16x16x32_bf16(a2[mi + 4], b1[ni], acc[mi + 4][ni], 0, 0, 0);
    __builtin_amdgcn_s_setprio(0);
    // a2[0..3] reads are not consumed until q3's MFMA -> force them complete
    // before q3's A0-stage can overwrite that LDS region (cross-wave WAR).
    asm volatile("s_waitcnt lgkmcnt(0)" ::: "memory");
    BAR();
    // ---- q3: no reads; stage A0(tau+2), B1(tau+2) -> dbuf d; vmcnt(6) ----
    __builtin_amdgcn_sched_barrier(0);
    STAGE(Ap, (d * 2 + 0) * 8192, t2, 0);
    STAGE(Bp, 32768 + (d * 2 + 1) * 8192, t2, 128);
    __builtin_amdgcn_sched_barrier(0);
    BAR();
    __builtin_amdgcn_s_setprio(1);
#pragma unroll
    for (int mi = 0; mi < 4; ++mi)
#pragma unroll
      for (int ni = 0; ni < 4; ++ni)
        acc[mi][ni] = __builtin_amdgcn_mfma_f32_16x16x32_bf16(a2[mi], b1[ni], acc[mi][ni], 0, 0, 0);
    __builtin_amdgcn_s_setprio(0);
    asm volatile("s_waitcnt vmcnt(6)" ::: "memory");  // never 0 in main loop (T4)
    BAR();
  };

  for (int tp = 0; tp < NKT / 2; ++tp) {
    TILE(0, 2 * tp);
    TILE(1, 2 * tp + 1);
  }

  asm volatile("s_waitcnt vmcnt(0)" ::: "memory");  // drain before epilogue/endpgm

  const int rbase = it * BM + wm * 128;
  const int cbase = nt * BN + wn * 64;
#pragma unroll
  for (int mi = 0; mi < 8; ++mi) {
#pragma unroll
    for (int ni = 0; ni < 4; ++ni) {
      const int col = cbase + ni * 16 + lrow;   // n = t*64 + o
      const int t = col >> 6, o = col & 63;
      const int row0 = rbase + mi * 16 + (c0 << 2);
      float* op = out + ((size_t)(b * Tt + t) * Nn + row0) * FOUT + o;
      f32x4 v = acc[mi][ni];
#pragma unroll
      for (int q = 0; q < 4; ++q)
        op[(size_t)q * FOUT] = fmaxf(v[q], 0.f);
    }
  }
}

// ---------------------------------------------------------------------------
// fallback (ws too small): slow but correct, pure f32
// ---------------------------------------------------------------------------
__global__ __launch_bounds__(128) void k_fallback(
    const float* __restrict__ x, const float* __restrict__ att,
    const float* __restrict__ cheb, const float* __restrict__ theta,
    float* __restrict__ out) {
  const int blk = blockIdx.x;  // (b, t, i)
  const int i = blk & 1023;
  const int bt = blk >> 10;
  const int t = bt % Tt, b = bt / Tt;
  __shared__ float rhs[KC * FIN];
  const int tid = threadIdx.x;
  if (tid < KC * FIN) {
    const int k = tid >> 5, f = tid & 31;
    const float* ar = att + ((size_t)b * Nn + i) * Nn;
    const float* cr = cheb + ((size_t)k * Nn + i) * Nn;
    const float* xr = x + ((size_t)(b * Tt + t) * Nn) * FIN + f;
    float s = 0.f;
    for (int j = 0; j < Nn; ++j) s = fmaf(ar[j] * cr[j], xr[(size_t)j * FIN], s);
    rhs[tid] = s;
  }
  __syncthreads();
  if (tid < FOUT) {
    float a = 0.f;
#pragma unroll
    for (int kf = 0; kf < KC * FIN; ++kf) a = fmaf(rhs[kf], theta[kf * FOUT + tid], a);
    out[((size_t)(b * Tt + t) * Nn + i) * FOUT + tid] = fmaxf(a, 0.f);
  }
}

extern "C" void kernel_launch(void* const* d_in, const int* in_sizes, int n_in,
                              void* d_out, int out_size, void* d_ws, size_t ws_size,
                              hipStream_t stream) {
  const float* x     = (const float*)d_in[0];
  const float* att   = (const float*)d_in[1];
  const float* cheb  = (const float*)d_in[2];
  const float* theta = (const float*)d_in[3];
  float* out = (float*)d_out;

  const size_t needA = (size_t)Bb * Nn * KJ * sizeof(unsigned short);  // 96 MB
  const size_t needY = (size_t)Bb * NO * KJ * sizeof(unsigned short);  // 72 MB
  if (ws_size >= needA + needY) {
    unsigned short* Acat = (unsigned short*)d_ws;
    unsigned short* Yw   = (unsigned short*)((char*)d_ws + needA);
    hipLaunchKernelGGL(k1_build_A, dim3(Bb * Nn * (Nn / 4) / 256), dim3(256), 0, stream,
                       att, cheb, Acat);
    hipLaunchKernelGGL(k2_build_Y, dim3(Bb * Tt * 2), dim3(256), 0, stream,
                       x, theta, Yw);
    hipLaunchKernelGGL(k3_gemm, dim3(Bb * (Nn / BM) * (NO / BN)), dim3(512), 0, stream,
                       Acat, Yw, out);
  } else {
    hipLaunchKernelGGL(k_fallback, dim3(Bb * Tt * Nn), dim3(128), 0, stream,
                       x, att, cheb, theta, out);
  }
}